// Round 8
// baseline (5050.791 us; speedup 1.0000x reference)
//
#include <hip/hip_runtime.h>
#include <stdint.h>

typedef unsigned int u32;
typedef unsigned long long u64;
typedef __attribute__((ext_vector_type(8))) short bf16x8;
typedef __attribute__((ext_vector_type(4))) float f32x4;
typedef __attribute__((ext_vector_type(4))) int i32x4;
typedef __attribute__((ext_vector_type(2))) int i32x2;

#define DEV static __device__ __forceinline__

DEV short f2bf(float f){ u32 u=__float_as_uint(f); return (short)((u + 0x7fffu + ((u>>16)&1u))>>16); }
DEV float bf2f(short s){ return __uint_as_float(((u32)(unsigned short)s)<<16); }
DEV float sig_p(float x){ return 1.f/(1.f+expf(-x)); }
DEV float tanh_fast(float x){ float e=__expf(2.f*x); return 1.f-2.f/(e+1.f); }

// relaxed agent-scope (LLC-coherent) accessors
DEV u32  cohl4(const u32* p){ return __hip_atomic_load(p, __ATOMIC_RELAXED, __HIP_MEMORY_SCOPE_AGENT); }
DEV void cohs4(u32* p, u32 v){ __hip_atomic_store(p, v, __ATOMIC_RELAXED, __HIP_MEMORY_SCOPE_AGENT); }
DEV void cohs8(void* p, u64 v){ __hip_atomic_store((u64*)p, v, __ATOMIC_RELAXED, __HIP_MEMORY_SCOPE_AGENT); }

// ---------------- convert / transpose kernels ----------------

__global__ void cvt1d(const float* __restrict__ in, short* __restrict__ out, int n){
  int i = blockIdx.x*256 + threadIdx.x;
  if (i < n) out[i] = f2bf(in[i]);
}

// in f32 [R][C] -> out bf16 [Cpad][R]
__global__ void tconv(const float* __restrict__ in, short* __restrict__ out, int R, int C, int Cpad){
  __shared__ float t[32][33];
  int tx = threadIdx.x, ty = threadIdx.y;
  int c0 = blockIdx.x*32, r0 = blockIdx.y*32;
#pragma unroll
  for (int j=0;j<4;++j){
    int r = r0 + ty + 8*j, c = c0 + tx;
    t[ty+8*j][tx] = (c < C) ? in[(size_t)r*C + c] : 0.f;
  }
  __syncthreads();
#pragma unroll
  for (int j=0;j<4;++j){
    int oc = c0 + ty + 8*j;
    out[(size_t)oc*R + r0 + tx] = f2bf(t[tx][ty+8*j]);
  }
}

// batched transpose: in bf16 [NB][Dd][32] -> out bf16 [NB*32][Dd]
__global__ void btrans(const short* __restrict__ in, short* __restrict__ out, int Dd){
  __shared__ short t[32][33];
  int tx = threadIdx.x, ty = threadIdx.y;
  int d0 = blockIdx.x*32, s = blockIdx.y;
#pragma unroll
  for (int j=0;j<4;++j)
    t[ty+8*j][tx] = in[((size_t)s*Dd + d0 + ty + 8*j)*32 + tx];
  __syncthreads();
#pragma unroll
  for (int j=0;j<4;++j)
    out[((size_t)(s*32 + ty + 8*j))*Dd + d0 + tx] = t[tx][ty+8*j];
}

// [s][1536][32] -> [b][1536][128]
__global__ void etrans(const short* __restrict__ in, short* __restrict__ out){
  __shared__ short t[128][33];
  int c = blockIdx.x, tid = threadIdx.x;
#pragma unroll
  for (int i=0;i<16;++i){
    int idx = tid + i*256;
    t[idx>>5][idx&31] = in[((size_t)(idx>>5)*1536 + c)*32 + (idx&31)];
  }
  __syncthreads();
#pragma unroll
  for (int i=0;i<16;++i){
    int idx = tid + i*256;
    out[((size_t)(idx>>7)*1536 + c)*128 + (idx&127)] = t[idx&127][idx>>7];
  }
}

__global__ void embed_k(const int* __restrict__ tok, const float* __restrict__ emb, short* __restrict__ X){
  int row = blockIdx.x;               // (s,b)
  int s = row >> 5, b = row & 31;
  int tv = tok[b*128 + s];
  X[(size_t)row*256 + threadIdx.x] = f2bf(emb[(size_t)tv*256 + threadIdx.x]);
}

// ---------------- MFMA GEMM  C = A[M,K] * BT[Npad][K] ----------------
template<int MODE>
__global__ __launch_bounds__(256) void gemm_k(
  const short* __restrict__ A, const short* __restrict__ BT,
  const float* __restrict__ bias, void* __restrict__ outp,
  float* __restrict__ psum, int Nreal, int K, int Ntot)
{
  const int m0 = blockIdx.y * 128, n0 = blockIdx.x * 128;
  const int tid = threadIdx.x, l = tid & 63, wv = tid >> 6;
  const int wm = wv >> 1, wn = wv & 1;
  __shared__ __align__(16) short As[128*64];
  __shared__ __align__(16) short Bs[128*64];
  f32x4 acc[4][4];
#pragma unroll
  for (int i=0;i<4;++i)
#pragma unroll
    for (int j=0;j<4;++j) acc[i][j] = (f32x4){0.f,0.f,0.f,0.f};

  const int nkb = K >> 6;
  for (int kb=0; kb<nkb; ++kb){
#pragma unroll
    for (int i=0;i<4;++i){
      int si = tid + i*256;
      int row = si >> 3, seg = si & 7;
      u32 off = (u32)(row*128 + seg*16) ^ (u32)((row&7)<<4);
      *(i32x4*)((char*)As + off) = *(const i32x4*)(A + (size_t)(m0+row)*K + kb*64 + seg*8);
      *(i32x4*)((char*)Bs + off) = *(const i32x4*)(BT + (size_t)(n0+row)*K + kb*64 + seg*8);
    }
    __syncthreads();
#pragma unroll
    for (int kt=0; kt<2; ++kt){
      bf16x8 af[4], bfv[4];
      int seg = kt*4 + (l>>4);
#pragma unroll
      for (int f=0; f<4; ++f){
        int ra = wm*64 + f*16 + (l&15);
        af[f]  = *(const bf16x8*)((char*)As + (((u32)(ra*128 + seg*16)) ^ ((u32)(ra&7)<<4)));
        int rb = wn*64 + f*16 + (l&15);
        bfv[f] = *(const bf16x8*)((char*)Bs + (((u32)(rb*128 + seg*16)) ^ ((u32)(rb&7)<<4)));
      }
#pragma unroll
      for (int mf=0; mf<4; ++mf)
#pragma unroll
        for (int nf=0; nf<4; ++nf)
          acc[mf][nf] = __builtin_amdgcn_mfma_f32_16x16x32_bf16(af[mf], bfv[nf], acc[mf][nf], 0,0,0);
    }
    __syncthreads();
  }

  if (MODE == 1){
    short* oT = (short*)outp;
#pragma unroll
    for (int mf=0; mf<4; ++mf){
      int r0 = m0 + wm*64 + mf*16 + ((l>>4)<<2);
      int s = r0 >> 5, b0 = r0 & 31;
#pragma unroll
      for (int nf=0; nf<4; ++nf){
        int col = n0 + wn*64 + nf*16 + (l&15);
        float bv = bias ? bias[col] : 0.f;
        short tmp[4];
#pragma unroll
        for (int j=0;j<4;++j) tmp[j] = f2bf(acc[mf][nf][j] + bv);
        *(i32x2*)(oT + ((size_t)s*Ntot + col)*32 + b0) = *(i32x2*)tmp;
      }
    }
  } else if (MODE == 3){
    short* o = (short*)outp;
#pragma unroll
    for (int mf=0; mf<4; ++mf){
      int r0 = m0 + wm*64 + mf*16 + ((l>>4)<<2);
#pragma unroll
      for (int nf=0; nf<4; ++nf){
        int col = n0 + wn*64 + nf*16 + (l&15);
        if (col < Nreal){
          float bv = bias ? bias[col] : 0.f;
#pragma unroll
          for (int j=0;j<4;++j) o[(size_t)(r0+j)*Nreal + col] = f2bf(acc[mf][nf][j] + bv);
        }
      }
    }
  } else { // MODE 2
    float* o = (float*)outp;
    int ncb = gridDim.x;
    float rs[4][4];
#pragma unroll
    for (int i=0;i<4;++i)
#pragma unroll
      for (int j=0;j<4;++j) rs[i][j]=0.f;
#pragma unroll
    for (int mf=0; mf<4; ++mf){
      int r0 = m0 + wm*64 + mf*16 + ((l>>4)<<2);
      int s = r0 >> 5, b0 = r0 & 31;
#pragma unroll
      for (int nf=0; nf<4; ++nf){
        int col = n0 + wn*64 + nf*16 + (l&15);
        if (col < Nreal){
          float bv = bias[col];
#pragma unroll
          for (int j=0;j<4;++j){
            float e = __expf(acc[mf][nf][j] + bv);
            o[(size_t)((b0+j)*128 + s)*Nreal + col] = e;
            rs[mf][j] += e;
          }
        }
      }
    }
#pragma unroll
    for (int mf=0; mf<4; ++mf)
#pragma unroll
      for (int j=0;j<4;++j){
        float v = rs[mf][j];
        v += __shfl_xor(v,1); v += __shfl_xor(v,2); v += __shfl_xor(v,4); v += __shfl_xor(v,8);
        if ((l&15)==0){
          int r = m0 + wm*64 + mf*16 + ((l>>4)<<2) + j;
          int orow = (r&31)*128 + (r>>5);
          psum[(size_t)orow*(2*ncb) + blockIdx.x*2 + wn] = v;
        }
      }
  }
}

// ---------------- encoder scan: 32 WGs (16/dir) x 512 thr, TAGGED words ----------------
// band: u32 [2 dir][2 slot][32 b][512 k], word = (bf16 h << 16) | step_tag
__global__ __launch_bounds__(512,1) void enc_scan(
  const short* __restrict__ gxfT, const short* __restrict__ gxbT,
  const short* __restrict__ WhfT, const short* __restrict__ WhbT,
  const float* __restrict__ brf, const float* __restrict__ brb,
  u32* __restrict__ band, float* __restrict__ hfin,
  short* __restrict__ encT)
{
  __shared__ __align__(16) char Asb[32*1024];
  __shared__ float accL[96][36];
  __shared__ float brL[96];
  const int tid = threadIdx.x, wg = blockIdx.x;
  const int dir = wg >> 4, j = wg & 15;
  const short* gxT = dir ? gxbT : gxfT;
  const short* WT  = dir ? WhbT : WhfT;
  const float* br  = dir ? brb  : brf;
  u32* bd = band + (size_t)dir*32768;
  const int l = tid & 63, wv = tid >> 6;

  if (tid < 96) brL[tid] = br[(tid>>5)*512 + j*32 + (tid&31)];

  bf16x8 bfr[2][16];
  if (wv < 3){
#pragma unroll
    for (int p=0;p<2;++p){
      int gcol = wv*512 + j*32 + p*16 + (l&15);
      const short* bp = WT + (size_t)gcol*512 + ((l>>4)<<3);
#pragma unroll
      for (int kt=0; kt<16; ++kt) bfr[p][kt] = *(const bf16x8*)(bp + kt*32);
    }
  }

  const int pb = tid & 31, php = tid >> 5;       // publish mapping
  const int sb = tid >> 4, sk0 = (tid & 15)*32;  // stage mapping
  float hreg[2] = {0.f, 0.f};

  for (int t=0; t<128; ++t){
    const int s = dir ? (127-t) : t;
    // stage h_t: tagged poll-retry, then pack into LDS (bf16, swizzled)
    {
      const u32* src = bd + (size_t)(t&1)*16384 + sb*512 + sk0;
      u32 w[32];
#pragma unroll
      for (int i=0;i<32;++i) w[i] = cohl4(src+i);
#pragma unroll
      for (int i=0;i<32;++i){ while ((w[i]&0xffffu) != (u32)t) w[i] = cohl4(src+i); }
#pragma unroll
      for (int i=0;i<16;++i){
        u32 p = (w[2*i]>>16) | (w[2*i+1] & 0xffff0000u);
        *(u32*)(Asb + (((u32)(sb*1024 + (sk0+2*i)*2)) ^ ((u32)(sb&15)<<4))) = p;
      }
    }
    __syncthreads();
    if (wv < 3){
      f32x4 acc[2][2];
#pragma unroll
      for (int m=0;m<2;++m){ acc[m][0]=(f32x4){0,0,0,0}; acc[m][1]=(f32x4){0,0,0,0}; }
#pragma unroll
      for (int kt=0; kt<16; ++kt){
#pragma unroll
        for (int m=0;m<2;++m){
          int row = m*16 + (l&15);
          int kbyte = (kt*4 + (l>>4))*16;
          bf16x8 af = *(const bf16x8*)(Asb + (((u32)(row*1024 + kbyte)) ^ ((u32)(row&15)<<4)));
          acc[m][0] = __builtin_amdgcn_mfma_f32_16x16x32_bf16(af, bfr[0][kt], acc[m][0], 0,0,0);
          acc[m][1] = __builtin_amdgcn_mfma_f32_16x16x32_bf16(af, bfr[1][kt], acc[m][1], 0,0,0);
        }
      }
#pragma unroll
      for (int m=0;m<2;++m)
#pragma unroll
        for (int p=0;p<2;++p)
          *(f32x4*)&accL[wv*32 + p*16 + (l&15)][m*16 + ((l>>4)<<2)] = acc[m][p];
    }
    __syncthreads();
    // pointwise + immediate tagged publish
    short obf[2];
    {
      int b = pb, hc0 = php*2;
#pragma unroll
      for (int q=0;q<2;++q){
        int hc = hc0 + q, hcol = j*32 + hc;
        float xz = bf2f(gxT[((size_t)s*1536 + hcol)*32 + b]);
        float xr = bf2f(gxT[((size_t)s*1536 + 512 + hcol)*32 + b]);
        float xh = bf2f(gxT[((size_t)s*1536 + 1024 + hcol)*32 + b]);
        float gz = accL[hc][b]    + brL[hc];
        float gr = accL[32+hc][b] + brL[32+hc];
        float gh = accL[64+hc][b] + brL[64+hc];
        float z = sig_p(xz + gz);
        float r = sig_p(xr + gr);
        float hcand = tanhf(xh + r*gh);
        float hn = z*hreg[q] + (1.f-z)*hcand;
        hreg[q] = hn;
        obf[q] = f2bf(hn);
      }
      u32 w0 = ((u32)(unsigned short)obf[0]<<16) | (u32)(t+1);
      u32 w1 = ((u32)(unsigned short)obf[1]<<16) | (u32)(t+1);
      cohs8(bd + (size_t)((t+1)&1)*16384 + b*512 + j*32 + hc0, ((u64)w1<<32)|(u64)w0);
    }
    // off-critical-path stores
    {
      int b = pb, hc0 = php*2;
      encT[((size_t)s*1024 + dir*512 + (j*32+hc0))*32 + b]   = obf[0];
      encT[((size_t)s*1024 + dir*512 + (j*32+hc0+1))*32 + b] = obf[1];
      if (dir && t == 127){
        hfin[(j*32+hc0)*32 + b]   = hreg[0];
        hfin[(j*32+hc0+1)*32 + b] = hreg[1];
      }
    }
    __syncthreads();   // protect Asb reuse
  }
}

// ---------------- decoder init: tagged slot0 from hfin (tag 0) ----------------
__global__ void dec_init(const float* __restrict__ hfin, u32* __restrict__ band){
  int i = blockIdx.x*256 + threadIdx.x;   // 16384 = 32 b x 512 k
  int b = i >> 9, k = i & 511;
  band[b*512 + k] = ((u32)(unsigned short)f2bf(hfin[(size_t)k*32 + b])<<16);
}

// ---------------- decoder scan: 48 WGs x 512 thr, TAGGED words ----------------
// wg 0..15 : gh WG j: poll h_t -> MFMA (M=32 via 2 tiles) -> tagged GHt words
// wg 16..47: attn+GRU WG b: attention + pointwise, owns h[b] in LDS
// hband: u32 [2 slot][32 b][512 k]  word=(bf16<<16)|tag   (h_t tag = t)
// GHt:   u32 [32 b][1536 gcol]      word=(bf16<<16)|tag   (GH_t tag = t+1)
__global__ __launch_bounds__(512,1) void dec_scan(
  const short* __restrict__ gxeR,   // [(t*32+b)][1536] bf16 (incl bi_d)
  const short* __restrict__ encx,   // [b][1536][128] bf16
  const short* __restrict__ WhdT,   // [1536][512] bf16
  const float* __restrict__ brd,
  const short* __restrict__ Wa, const short* __restrict__ Uenc, const float* __restrict__ Va,
  const float* __restrict__ hfin,   // [512][32] f32
  u32* __restrict__ hband, u32* __restrict__ GHt,
  short* __restrict__ decRow)
{
  // gh-WG shared
  __shared__ __align__(16) char Asb[32*1024];
  // attn-WG shared
  __shared__ float hs[512];
  __shared__ float gxc[1536];
  __shared__ float brA[1536];
  __shared__ float whp[128*5];
  __shared__ float whv[128];
  __shared__ float scp[128*5];
  __shared__ float sc[128];
  __shared__ float red[4];
  __shared__ float vL[128];
  __shared__ float aL[128];

  const int tid = threadIdx.x, wg = blockIdx.x;
  const int l = tid & 63, wv = tid >> 6;

  if (wg < 16){
    // ---- gh WG j: 6 waves x one 16-col n-tile x TWO 16-batch m-tiles ----
    const int j = wg;
    const int colbase = (wv>>1)*512 + j*32 + ((wv&1)<<4);   // valid for wv<6
    bf16x8 bfr[16];
    if (wv < 6){
      const short* bp = WhdT + (size_t)(colbase + (l&15))*512 + ((l>>4)<<3);
#pragma unroll
      for (int kt=0; kt<16; ++kt) bfr[kt] = *(const bf16x8*)(bp + kt*32);
    }
    const int sb = tid >> 4, sk0 = (tid & 15)*32;
    for (int t=0; t<128; ++t){
      // stage h_t (tagged poll-retry)
      {
        const u32* src = hband + (size_t)(t&1)*16384 + sb*512 + sk0;
        u32 w[32];
#pragma unroll
        for (int i=0;i<32;++i) w[i] = cohl4(src+i);
#pragma unroll
        for (int i=0;i<32;++i){ while ((w[i]&0xffffu) != (u32)t) w[i] = cohl4(src+i); }
#pragma unroll
        for (int i=0;i<16;++i){
          u32 p = (w[2*i]>>16) | (w[2*i+1] & 0xffff0000u);
          *(u32*)(Asb + (((u32)(sb*1024 + (sk0+2*i)*2)) ^ ((u32)(sb&15)<<4))) = p;
        }
      }
      __syncthreads();
      if (wv < 6){
        f32x4 acc0 = (f32x4){0.f,0.f,0.f,0.f};
        f32x4 acc1 = (f32x4){0.f,0.f,0.f,0.f};
#pragma unroll
        for (int kt=0; kt<16; ++kt){
          int kbyte = (kt*32 + ((l>>4)<<3))*2;
          int r0 = l & 15, r1 = 16 + (l & 15);
          bf16x8 af0 = *(const bf16x8*)(Asb + (((u32)(r0*1024 + kbyte)) ^ ((u32)(r0&15)<<4)));
          bf16x8 af1 = *(const bf16x8*)(Asb + (((u32)(r1*1024 + kbyte)) ^ ((u32)(r1&15)<<4)));
          acc0 = __builtin_amdgcn_mfma_f32_16x16x32_bf16(af0, bfr[kt], acc0, 0,0,0);
          acc1 = __builtin_amdgcn_mfma_f32_16x16x32_bf16(af1, bfr[kt], acc1, 0,0,0);
        }
        // publish: batch = m*16 + (l>>4)*4 + r, gcol = colbase + (l&15), tag t+1
#pragma unroll
        for (int r=0;r<4;++r){
          u32 wd0 = ((u32)(unsigned short)f2bf(acc0[r])<<16) | (u32)(t+1);
          cohs4(&GHt[(size_t)((l>>4)*4 + r)*1536 + colbase + (l&15)], wd0);
          u32 wd1 = ((u32)(unsigned short)f2bf(acc1[r])<<16) | (u32)(t+1);
          cohs4(&GHt[(size_t)(16 + (l>>4)*4 + r)*1536 + colbase + (l&15)], wd1);
        }
      }
      __syncthreads();   // protect Asb reuse
    }
  } else {
    // ---- attn+GRU WG, batch b ----
    const int b = wg - 16;
    u32 wa[64];
    {
      const u32* wp = (const u32*)(Wa + (size_t)(tid&127)*512 + (tid>>7)*128);
#pragma unroll
      for (int i=0;i<64;++i) wa[i] = wp[i];
    }
    u32 ue[16];
    {
      int s = tid & 127, aq = tid >> 7;
      const u32* up = (const u32*)(Uenc + ((size_t)(s*32 + b))*128 + aq*32);
#pragma unroll
      for (int i=0;i<16;++i) ue[i] = up[i];
    }
    if (tid < 128) vL[tid] = Va[tid];
    for (int i = tid; i < 1536; i += 512) brA[i] = brd[i];
    hs[tid] = hfin[(size_t)tid*32 + b];
    const short* eb = encx + (size_t)b*1536*128;
    __syncthreads();

    for (int t=0; t<128; ++t){
      // wh = h @ Wa^T (k split 4-way)  [h local in LDS]
      {
        int a = tid & 127, kq2 = tid >> 7;
        float p = 0.f;
        const float* hp2 = &hs[kq2*128];
#pragma unroll 8
        for (int i=0;i<64;++i){
          u32 w2 = wa[i];
          float2 h2 = *(const float2*)(hp2 + 2*i);
          p += bf2f((short)(w2 & 0xffff))*h2.x + bf2f((short)(w2 >> 16))*h2.y;
        }
        whp[a*5 + kq2] = p;
      }
      __syncthreads();
      if (tid < 128) whv[tid] = whp[tid*5]+whp[tid*5+1]+whp[tid*5+2]+whp[tid*5+3];
      __syncthreads();
      // score_s = sum_a tanh(wh_a + Uenc) * v_a (a split 4-way)
      {
        int s = tid & 127, aq = tid >> 7;
        float p = 0.f;
#pragma unroll 4
        for (int i=0;i<16;++i){
          u32 u2 = ue[i];
          int a0 = aq*32 + 2*i;
          p += tanh_fast(whv[a0]   + bf2f((short)(u2 & 0xffff))) * vL[a0];
          p += tanh_fast(whv[a0+1] + bf2f((short)(u2 >> 16)))    * vL[a0+1];
        }
        scp[s*5 + aq] = p;
      }
      __syncthreads();
      if (tid < 128) sc[tid] = scp[tid*5]+scp[tid*5+1]+scp[tid*5+2]+scp[tid*5+3];
      __syncthreads();
      float ev = 0.f;
      if (tid < 128){
        float v = sc[tid], mx = v;
#pragma unroll
        for (int d2=32; d2; d2>>=1) mx = fmaxf(mx, __shfl_xor(mx, d2));
        if ((tid & 63) == 0) red[tid>>6] = mx;
      }
      __syncthreads();
      if (tid < 128){
        float mx = fmaxf(red[0], red[1]);
        ev = __expf(sc[tid] - mx);
        float sm = ev;
#pragma unroll
        for (int d2=32; d2; d2>>=1) sm += __shfl_xor(sm, d2);
        if ((tid & 63) == 0) red[2 + (tid>>6)] = sm;
      }
      __syncthreads();
      if (tid < 128) aL[tid] = ev / (red[2] + red[3]);
      __syncthreads();
      // gxctx: 3 cols/thread from L2-resident ENCX slice
      {
        int col = tid*3;
        float a0=0.f, a1=0.f, a2=0.f;
        const short* e0 = eb + (size_t)col*128;
#pragma unroll
        for (int sb2=0; sb2<16; ++sb2){
          f32x4 av0 = *(const f32x4*)&aL[sb2*8];
          f32x4 av1 = *(const f32x4*)&aL[sb2*8+4];
          bf16x8 ev0 = *(const bf16x8*)(e0 + sb2*8);
          bf16x8 ev1 = *(const bf16x8*)(e0 + 128 + sb2*8);
          bf16x8 ev2 = *(const bf16x8*)(e0 + 256 + sb2*8);
#pragma unroll
          for (int i=0;i<4;++i){
            a0 += bf2f(ev0[i])*av0[i]; a1 += bf2f(ev1[i])*av0[i]; a2 += bf2f(ev2[i])*av0[i];
            a0 += bf2f(ev0[4+i])*av1[i]; a1 += bf2f(ev1[4+i])*av1[i]; a2 += bf2f(ev2[4+i])*av1[i];
          }
        }
        gxc[col] = a0; gxc[col+1] = a1; gxc[col+2] = a2;
      }
      __syncthreads();
      // prefetch gx (independent of GH)
      const short* gx = gxeR + ((size_t)t*32 + b)*1536;
      float gx0 = bf2f(gx[tid])        + gxc[tid];
      float gx1 = bf2f(gx[512 + tid])  + gxc[512 + tid];
      float gx2 = bf2f(gx[1024 + tid]) + gxc[1024 + tid];
      // poll own GH words (tag t+1), decode, pointwise, publish h_{t+1}
      short mybf;
      {
        const u32* gp = GHt + (size_t)b*1536 + tid;
        u32 g0 = cohl4(gp), g1 = cohl4(gp+512), g2 = cohl4(gp+1024);
        u32 want = (u32)(t+1);
        while ((g0&0xffffu) != want) g0 = cohl4(gp);
        while ((g1&0xffffu) != want) g1 = cohl4(gp+512);
        while ((g2&0xffffu) != want) g2 = cohl4(gp+1024);
        float gh0 = bf2f((short)(g0>>16));
        float gh1 = bf2f((short)(g1>>16));
        float gh2 = bf2f((short)(g2>>16));
        float z = sig_p(gx0 + gh0 + brA[tid]);
        float r = sig_p(gx1 + gh1 + brA[512 + tid]);
        float hcand = tanhf(gx2 + r*(gh2 + brA[1024 + tid]));
        float hp = hs[tid];
        float hn = z*hp + (1.f-z)*hcand;
        mybf = f2bf(hn);
        cohs4(&hband[(size_t)((t+1)&1)*16384 + b*512 + tid],
              ((u32)(unsigned short)mybf<<16) | (u32)(t+1));
        hs[tid] = hn;
      }
      decRow[((size_t)t*32 + b)*512 + tid] = mybf;   // off critical path
      __syncthreads();                               // hs ready for next wh
    }
  }
}

// ---------------- softmax finish ----------------
__global__ void scale_rows(float* __restrict__ out, const float* __restrict__ psum,
                           int ncols, int w){
  int r = blockIdx.x;
  __shared__ float ssum[256];
  float s = 0.f;
  for (int i = threadIdx.x; i < w; i += 256) s += psum[(size_t)r*w + i];
  ssum[threadIdx.x] = s; __syncthreads();
  for (int d = 128; d; d >>= 1){
    if (threadIdx.x < d) ssum[threadIdx.x] += ssum[threadIdx.x + d];
    __syncthreads();
  }
  float v = 1.f/ssum[0];
  float* p = out + (size_t)r*ncols;
  for (int i = threadIdx.x; i < ncols; i += 256) p[i] *= v;
}

// ---------------- host ----------------
extern "C" void kernel_launch(void* const* d_in, const int* in_sizes, int n_in,
                              void* d_out, int out_size, void* d_ws, size_t ws_size,
                              hipStream_t stream)
{
  const int*   tokens=(const int*)  d_in[0];
  const float* emb  =(const float*)d_in[1];
  const float* Wx_f =(const float*)d_in[2];
  const float* Wh_f =(const float*)d_in[3];
  const float* bi_f =(const float*)d_in[4];
  const float* br_f =(const float*)d_in[5];
  const float* Wx_b =(const float*)d_in[6];
  const float* Wh_b =(const float*)d_in[7];
  const float* bi_b =(const float*)d_in[8];
  const float* br_b =(const float*)d_in[9];
  const float* W_a  =(const float*)d_in[10];
  const float* U_a  =(const float*)d_in[11];
  const float* V_a  =(const float*)d_in[12];
  const float* Wx_d =(const float*)d_in[13];
  const float* Wh_d =(const float*)d_in[14];
  const float* bi_d =(const float*)d_in[15];
  const float* br_d =(const float*)d_in[16];
  const float* Wo   =(const float*)d_in[17];
  const float* bo   =(const float*)d_in[18];

  const int NV = 32001, NVP = 32128, NCB = 251;

  char* base = (char*)d_ws; size_t off = 0;
  auto alloc = [&](size_t bytes)->char*{
    off = (off + 255) & ~(size_t)255;
    char* p = base + off; off += bytes; return p;
  };
  u32*   band_e = (u32*)  alloc((size_t)2*2*16384*4);   // [2 dir][2 slot][32][512]
  u32*   band_d = (u32*)  alloc((size_t)2*16384*4);     // [2 slot][32][512]
  u32*   GHt    = (u32*)  alloc((size_t)32*1536*4);     // [32][1536]
  float* hfin   = (float*)alloc((size_t)512*32*4);
  short* X      = (short*)alloc((size_t)4096*256*2);
  short* WxfT   = (short*)alloc((size_t)1536*256*2);
  short* WxbT   = (short*)alloc((size_t)1536*256*2);
  short* WhfT   = (short*)alloc((size_t)1536*512*2);
  short* WhbT   = (short*)alloc((size_t)1536*512*2);
  short* WhdT   = (short*)alloc((size_t)1536*512*2);
  short* WxeT   = (short*)alloc((size_t)1536*1024*2);
  short* WxcT   = (short*)alloc((size_t)1536*1024*2);
  short* WoT    = (short*)alloc((size_t)NVP*512*2);
  short* UaB    = (short*)alloc((size_t)128*1024*2);
  short* WaB    = (short*)alloc((size_t)128*512*2);
  short* gxfT   = (short*)alloc((size_t)128*1536*32*2);
  short* gxbT   = (short*)alloc((size_t)128*1536*32*2);
  short* encT   = (short*)alloc((size_t)128*1024*32*2);
  short* encRow = (short*)alloc((size_t)4096*1024*2);
  short* Uenc   = (short*)alloc((size_t)4096*128*2);
  short* gxeR   = (short*)alloc((size_t)4096*1536*2);
  short* encxT1 = (short*)alloc((size_t)128*1536*32*2);
  short* encx   = (short*)alloc((size_t)32*1536*128*2);
  short* decRow = (short*)alloc((size_t)4096*512*2);
  float* psum   = (float*)alloc((size_t)4096*2*NCB*4);

  hipMemsetAsync(band_e, 0, (size_t)2*2*16384*4, stream);   // slot0 = h0 zeros, tag 0
  hipMemsetAsync(band_d, 0, (size_t)2*16384*4, stream);
  hipMemsetAsync(GHt,    0, (size_t)32*1536*4, stream);

  // weight conversions (all BT = [N][K] bf16)
  tconv<<<dim3(1536/32,256/32),dim3(32,8),0,stream>>>(Wx_f, WxfT, 256, 1536, 1536);
  tconv<<<dim3(1536/32,256/32),dim3(32,8),0,stream>>>(Wx_b, WxbT, 256, 1536, 1536);
  tconv<<<dim3(1536/32,512/32),dim3(32,8),0,stream>>>(Wh_f, WhfT, 512, 1536, 1536);
  tconv<<<dim3(1536/32,512/32),dim3(32,8),0,stream>>>(Wh_b, WhbT, 512, 1536, 1536);
  tconv<<<dim3(1536/32,512/32),dim3(32,8),0,stream>>>(Wh_d, WhdT, 512, 1536, 1536);
  tconv<<<dim3(1536/32,1024/32),dim3(32,8),0,stream>>>(Wx_d,                    WxeT, 1024, 1536, 1536);
  tconv<<<dim3(1536/32,1024/32),dim3(32,8),0,stream>>>(Wx_d+(size_t)1024*1536,  WxcT, 1024, 1536, 1536);
  tconv<<<dim3(NVP/32,512/32),dim3(32,8),0,stream>>>(Wo, WoT, 512, NV, NVP);
  cvt1d<<<(128*512+255)/256,256,0,stream>>>(W_a, WaB, 128*512);
  cvt1d<<<(128*1024+255)/256,256,0,stream>>>(U_a, UaB, 128*1024);

  embed_k<<<4096,256,0,stream>>>(tokens, emb, X);

  gemm_k<1><<<dim3(12,32),256,0,stream>>>(X, WxfT, bi_f, gxfT, nullptr, 1536, 256, 1536);
  gemm_k<1><<<dim3(12,32),256,0,stream>>>(X, WxbT, bi_b, gxbT, nullptr, 1536, 256, 1536);

  enc_scan<<<32,512,0,stream>>>(gxfT, gxbT, WhfT, WhbT, br_f, br_b,
                                band_e, hfin, encT);

  btrans<<<dim3(1024/32,128),dim3(32,8),0,stream>>>(encT, encRow, 1024);

  gemm_k<3><<<dim3(1,32),256,0,stream>>>(encRow, UaB, nullptr, Uenc, nullptr, 128, 1024, 128);
  gemm_k<3><<<dim3(12,32),256,0,stream>>>(encRow, WxeT, bi_d, gxeR, nullptr, 1536, 1024, 1536);
  gemm_k<1><<<dim3(12,32),256,0,stream>>>(encRow, WxcT, nullptr, encxT1, nullptr, 1536, 1024, 1536);
  etrans<<<1536,256,0,stream>>>(encxT1, encx);

  dec_init<<<64,256,0,stream>>>(hfin, band_d);

  dec_scan<<<48,512,0,stream>>>(gxeR, encx, WhdT, br_d, WaB, Uenc, V_a,
                                hfin, band_d, GHt, decRow);

  gemm_k<2><<<dim3(NCB,32),256,0,stream>>>(decRow, WoT, bo, d_out, psum, NV, 512, NV);

  scale_rows<<<4096,256,0,stream>>>((float*)d_out, psum, NV, 2*NCB);
}

// Round 9
// 4940.306 us; speedup vs baseline: 1.0224x; 1.0224x over previous
//
#include <hip/hip_runtime.h>
#include <stdint.h>

typedef unsigned int u32;
typedef unsigned long long u64;
typedef __attribute__((ext_vector_type(8))) short bf16x8;
typedef __attribute__((ext_vector_type(4))) float f32x4;
typedef __attribute__((ext_vector_type(4))) int i32x4;
typedef __attribute__((ext_vector_type(2))) int i32x2;

#define DEV static __device__ __forceinline__

DEV short f2bf(float f){ u32 u=__float_as_uint(f); return (short)((u + 0x7fffu + ((u>>16)&1u))>>16); }
DEV float bf2f(short s){ return __uint_as_float(((u32)(unsigned short)s)<<16); }
DEV float sig_p(float x){ return 1.f/(1.f+expf(-x)); }
DEV float tanh_fast(float x){ float e=__expf(2.f*x); return 1.f-2.f/(e+1.f); }

// relaxed agent-scope (LLC-coherent) accessors
DEV u32  cohl4(const u32* p){ return __hip_atomic_load(p, __ATOMIC_RELAXED, __HIP_MEMORY_SCOPE_AGENT); }
DEV void cohs4(u32* p, u32 v){ __hip_atomic_store(p, v, __ATOMIC_RELAXED, __HIP_MEMORY_SCOPE_AGENT); }
DEV void cohs8(void* p, u64 v){ __hip_atomic_store((u64*)p, v, __ATOMIC_RELAXED, __HIP_MEMORY_SCOPE_AGENT); }
DEV void doneadd(u32* p){ __hip_atomic_fetch_add(p, 1u, __ATOMIC_RELAXED, __HIP_MEMORY_SCOPE_AGENT); }

// DVFS filler: keep CU busy with FMA chain; poll isolated done word rarely.
__shared__ int filler_fin;
DEV void filler_spin(const u32* done, u32 target){
  if (threadIdx.x == 0) filler_fin = 0;
  __syncthreads();
  float x = (float)threadIdx.x + 1.f;
  for (;;){
#pragma unroll 8
    for (int i=0;i<1024;++i) x = __builtin_fmaf(x, 1.0000001f, 1e-7f);
    asm volatile("" :: "v"(x));
    if (threadIdx.x == 0 && cohl4(done) >= target) filler_fin = 1;
    __syncthreads();
    if (filler_fin) return;
    __syncthreads();
  }
}

// ---------------- convert / transpose kernels ----------------

__global__ void cvt1d(const float* __restrict__ in, short* __restrict__ out, int n){
  int i = blockIdx.x*256 + threadIdx.x;
  if (i < n) out[i] = f2bf(in[i]);
}

// in f32 [R][C] -> out bf16 [Cpad][R]
__global__ void tconv(const float* __restrict__ in, short* __restrict__ out, int R, int C, int Cpad){
  __shared__ float t[32][33];
  int tx = threadIdx.x, ty = threadIdx.y;
  int c0 = blockIdx.x*32, r0 = blockIdx.y*32;
#pragma unroll
  for (int j=0;j<4;++j){
    int r = r0 + ty + 8*j, c = c0 + tx;
    t[ty+8*j][tx] = (c < C) ? in[(size_t)r*C + c] : 0.f;
  }
  __syncthreads();
#pragma unroll
  for (int j=0;j<4;++j){
    int oc = c0 + ty + 8*j;
    out[(size_t)oc*R + r0 + tx] = f2bf(t[tx][ty+8*j]);
  }
}

// batched transpose: in bf16 [NB][Dd][32] -> out bf16 [NB*32][Dd]
__global__ void btrans(const short* __restrict__ in, short* __restrict__ out, int Dd){
  __shared__ short t[32][33];
  int tx = threadIdx.x, ty = threadIdx.y;
  int d0 = blockIdx.x*32, s = blockIdx.y;
#pragma unroll
  for (int j=0;j<4;++j)
    t[ty+8*j][tx] = in[((size_t)s*Dd + d0 + ty + 8*j)*32 + tx];
  __syncthreads();
#pragma unroll
  for (int j=0;j<4;++j)
    out[((size_t)(s*32 + ty + 8*j))*Dd + d0 + tx] = t[tx][ty+8*j];
}

// [s][1536][32] -> [b][1536][128]
__global__ void etrans(const short* __restrict__ in, short* __restrict__ out){
  __shared__ short t[128][33];
  int c = blockIdx.x, tid = threadIdx.x;
#pragma unroll
  for (int i=0;i<16;++i){
    int idx = tid + i*256;
    t[idx>>5][idx&31] = in[((size_t)(idx>>5)*1536 + c)*32 + (idx&31)];
  }
  __syncthreads();
#pragma unroll
  for (int i=0;i<16;++i){
    int idx = tid + i*256;
    out[((size_t)(idx>>7)*1536 + c)*128 + (idx&127)] = t[idx&127][idx>>7];
  }
}

__global__ void embed_k(const int* __restrict__ tok, const float* __restrict__ emb, short* __restrict__ X){
  int row = blockIdx.x;               // (s,b)
  int s = row >> 5, b = row & 31;
  int tv = tok[b*128 + s];
  X[(size_t)row*256 + threadIdx.x] = f2bf(emb[(size_t)tv*256 + threadIdx.x]);
}

// ---------------- MFMA GEMM  C = A[M,K] * BT[Npad][K] ----------------
template<int MODE>
__global__ __launch_bounds__(256) void gemm_k(
  const short* __restrict__ A, const short* __restrict__ BT,
  const float* __restrict__ bias, void* __restrict__ outp,
  float* __restrict__ psum, int Nreal, int K, int Ntot)
{
  const int m0 = blockIdx.y * 128, n0 = blockIdx.x * 128;
  const int tid = threadIdx.x, l = tid & 63, wv = tid >> 6;
  const int wm = wv >> 1, wn = wv & 1;
  __shared__ __align__(16) short As[128*64];
  __shared__ __align__(16) short Bs[128*64];
  f32x4 acc[4][4];
#pragma unroll
  for (int i=0;i<4;++i)
#pragma unroll
    for (int j=0;j<4;++j) acc[i][j] = (f32x4){0.f,0.f,0.f,0.f};

  const int nkb = K >> 6;
  for (int kb=0; kb<nkb; ++kb){
#pragma unroll
    for (int i=0;i<4;++i){
      int si = tid + i*256;
      int row = si >> 3, seg = si & 7;
      u32 off = (u32)(row*128 + seg*16) ^ (u32)((row&7)<<4);
      *(i32x4*)((char*)As + off) = *(const i32x4*)(A + (size_t)(m0+row)*K + kb*64 + seg*8);
      *(i32x4*)((char*)Bs + off) = *(const i32x4*)(BT + (size_t)(n0+row)*K + kb*64 + seg*8);
    }
    __syncthreads();
#pragma unroll
    for (int kt=0; kt<2; ++kt){
      bf16x8 af[4], bfv[4];
      int seg = kt*4 + (l>>4);
#pragma unroll
      for (int f=0; f<4; ++f){
        int ra = wm*64 + f*16 + (l&15);
        af[f]  = *(const bf16x8*)((char*)As + (((u32)(ra*128 + seg*16)) ^ ((u32)(ra&7)<<4)));
        int rb = wn*64 + f*16 + (l&15);
        bfv[f] = *(const bf16x8*)((char*)Bs + (((u32)(rb*128 + seg*16)) ^ ((u32)(rb&7)<<4)));
      }
#pragma unroll
      for (int mf=0; mf<4; ++mf)
#pragma unroll
        for (int nf=0; nf<4; ++nf)
          acc[mf][nf] = __builtin_amdgcn_mfma_f32_16x16x32_bf16(af[mf], bfv[nf], acc[mf][nf], 0,0,0);
    }
    __syncthreads();
  }

  if (MODE == 1){
    short* oT = (short*)outp;
#pragma unroll
    for (int mf=0; mf<4; ++mf){
      int r0 = m0 + wm*64 + mf*16 + ((l>>4)<<2);
      int s = r0 >> 5, b0 = r0 & 31;
#pragma unroll
      for (int nf=0; nf<4; ++nf){
        int col = n0 + wn*64 + nf*16 + (l&15);
        float bv = bias ? bias[col] : 0.f;
        short tmp[4];
#pragma unroll
        for (int j=0;j<4;++j) tmp[j] = f2bf(acc[mf][nf][j] + bv);
        *(i32x2*)(oT + ((size_t)s*Ntot + col)*32 + b0) = *(i32x2*)tmp;
      }
    }
  } else if (MODE == 3){
    short* o = (short*)outp;
#pragma unroll
    for (int mf=0; mf<4; ++mf){
      int r0 = m0 + wm*64 + mf*16 + ((l>>4)<<2);
#pragma unroll
      for (int nf=0; nf<4; ++nf){
        int col = n0 + wn*64 + nf*16 + (l&15);
        if (col < Nreal){
          float bv = bias ? bias[col] : 0.f;
#pragma unroll
          for (int j=0;j<4;++j) o[(size_t)(r0+j)*Nreal + col] = f2bf(acc[mf][nf][j] + bv);
        }
      }
    }
  } else { // MODE 2
    float* o = (float*)outp;
    int ncb = gridDim.x;
    float rs[4][4];
#pragma unroll
    for (int i=0;i<4;++i)
#pragma unroll
      for (int j=0;j<4;++j) rs[i][j]=0.f;
#pragma unroll
    for (int mf=0; mf<4; ++mf){
      int r0 = m0 + wm*64 + mf*16 + ((l>>4)<<2);
      int s = r0 >> 5, b0 = r0 & 31;
#pragma unroll
      for (int nf=0; nf<4; ++nf){
        int col = n0 + wn*64 + nf*16 + (l&15);
        if (col < Nreal){
          float bv = bias[col];
#pragma unroll
          for (int j=0;j<4;++j){
            float e = __expf(acc[mf][nf][j] + bv);
            o[(size_t)((b0+j)*128 + s)*Nreal + col] = e;
            rs[mf][j] += e;
          }
        }
      }
    }
#pragma unroll
    for (int mf=0; mf<4; ++mf)
#pragma unroll
      for (int j=0;j<4;++j){
        float v = rs[mf][j];
        v += __shfl_xor(v,1); v += __shfl_xor(v,2); v += __shfl_xor(v,4); v += __shfl_xor(v,8);
        if ((l&15)==0){
          int r = m0 + wm*64 + mf*16 + ((l>>4)<<2) + j;
          int orow = (r&31)*128 + (r>>5);
          psum[(size_t)orow*(2*ncb) + blockIdx.x*2 + wn] = v;
        }
      }
  }
}

// ---------------- encoder scan: 32 worker WGs + DVFS fillers ----------------
// band: u32 [2 dir][2 slot][32 b][512 k], word = (bf16 h << 16) | step_tag
__global__ __launch_bounds__(512,1) void enc_scan(
  const short* __restrict__ gxfT, const short* __restrict__ gxbT,
  const short* __restrict__ WhfT, const short* __restrict__ WhbT,
  const float* __restrict__ brf, const float* __restrict__ brb,
  u32* __restrict__ band, float* __restrict__ hfin,
  short* __restrict__ encT, u32* __restrict__ dcnt)
{
  const int tid = threadIdx.x, wg = blockIdx.x;
  if (wg >= 32){ filler_spin(&dcnt[0], 32u); return; }

  __shared__ __align__(16) char Asb[32*1024];
  __shared__ float accL[96][36];
  __shared__ float brL[96];
  const int dir = wg >> 4, j = wg & 15;
  const short* gxT = dir ? gxbT : gxfT;
  const short* WT  = dir ? WhbT : WhfT;
  const float* br  = dir ? brb  : brf;
  u32* bd = band + (size_t)dir*32768;
  const int l = tid & 63, wv = tid >> 6;

  if (tid < 96) brL[tid] = br[(tid>>5)*512 + j*32 + (tid&31)];

  bf16x8 bfr[2][16];
  if (wv < 3){
#pragma unroll
    for (int p=0;p<2;++p){
      int gcol = wv*512 + j*32 + p*16 + (l&15);
      const short* bp = WT + (size_t)gcol*512 + ((l>>4)<<3);
#pragma unroll
      for (int kt=0; kt<16; ++kt) bfr[p][kt] = *(const bf16x8*)(bp + kt*32);
    }
  }

  const int pb = tid & 31, php = tid >> 5;       // publish mapping
  const int sb = tid >> 4, sk0 = (tid & 15)*32;  // stage mapping
  float hreg[2] = {0.f, 0.f};

  for (int t=0; t<128; ++t){
    const int s = dir ? (127-t) : t;
    // stage h_t: tagged poll-retry, then pack into LDS (bf16, swizzled)
    {
      const u32* src = bd + (size_t)(t&1)*16384 + sb*512 + sk0;
      u32 w[32];
#pragma unroll
      for (int i=0;i<32;++i) w[i] = cohl4(src+i);
#pragma unroll
      for (int i=0;i<32;++i){ while ((w[i]&0xffffu) != (u32)t) w[i] = cohl4(src+i); }
#pragma unroll
      for (int i=0;i<16;++i){
        u32 p = (w[2*i]>>16) | (w[2*i+1] & 0xffff0000u);
        *(u32*)(Asb + (((u32)(sb*1024 + (sk0+2*i)*2)) ^ ((u32)(sb&15)<<4))) = p;
      }
    }
    __syncthreads();
    if (wv < 3){
      f32x4 acc[2][2];
#pragma unroll
      for (int m=0;m<2;++m){ acc[m][0]=(f32x4){0,0,0,0}; acc[m][1]=(f32x4){0,0,0,0}; }
#pragma unroll
      for (int kt=0; kt<16; ++kt){
#pragma unroll
        for (int m=0;m<2;++m){
          int row = m*16 + (l&15);
          int kbyte = (kt*4 + (l>>4))*16;
          bf16x8 af = *(const bf16x8*)(Asb + (((u32)(row*1024 + kbyte)) ^ ((u32)(row&15)<<4)));
          acc[m][0] = __builtin_amdgcn_mfma_f32_16x16x32_bf16(af, bfr[0][kt], acc[m][0], 0,0,0);
          acc[m][1] = __builtin_amdgcn_mfma_f32_16x16x32_bf16(af, bfr[1][kt], acc[m][1], 0,0,0);
        }
      }
#pragma unroll
      for (int m=0;m<2;++m)
#pragma unroll
        for (int p=0;p<2;++p)
          *(f32x4*)&accL[wv*32 + p*16 + (l&15)][m*16 + ((l>>4)<<2)] = acc[m][p];
    }
    __syncthreads();
    // pointwise + immediate tagged publish
    short obf[2];
    {
      int b = pb, hc0 = php*2;
#pragma unroll
      for (int q=0;q<2;++q){
        int hc = hc0 + q, hcol = j*32 + hc;
        float xz = bf2f(gxT[((size_t)s*1536 + hcol)*32 + b]);
        float xr = bf2f(gxT[((size_t)s*1536 + 512 + hcol)*32 + b]);
        float xh = bf2f(gxT[((size_t)s*1536 + 1024 + hcol)*32 + b]);
        float gz = accL[hc][b]    + brL[hc];
        float gr = accL[32+hc][b] + brL[32+hc];
        float gh = accL[64+hc][b] + brL[64+hc];
        float z = sig_p(xz + gz);
        float r = sig_p(xr + gr);
        float hcand = tanhf(xh + r*gh);
        float hn = z*hreg[q] + (1.f-z)*hcand;
        hreg[q] = hn;
        obf[q] = f2bf(hn);
      }
      u32 w0 = ((u32)(unsigned short)obf[0]<<16) | (u32)(t+1);
      u32 w1 = ((u32)(unsigned short)obf[1]<<16) | (u32)(t+1);
      cohs8(bd + (size_t)((t+1)&1)*16384 + pb*512 + j*32 + php*2, ((u64)w1<<32)|(u64)w0);
    }
    // off-critical-path stores
    {
      int b = pb, hc0 = php*2;
      encT[((size_t)s*1024 + dir*512 + (j*32+hc0))*32 + b]   = obf[0];
      encT[((size_t)s*1024 + dir*512 + (j*32+hc0+1))*32 + b] = obf[1];
      if (dir && t == 127){
        hfin[(j*32+hc0)*32 + b]   = hreg[0];
        hfin[(j*32+hc0+1)*32 + b] = hreg[1];
      }
    }
    __syncthreads();   // protect Asb reuse
  }
  if (tid == 0) doneadd(&dcnt[0]);
}

// ---------------- decoder init: tagged slot0 from hfin (tag 0) ----------------
__global__ void dec_init(const float* __restrict__ hfin, u32* __restrict__ band){
  int i = blockIdx.x*256 + threadIdx.x;   // 16384 = 32 b x 512 k
  int b = i >> 9, k = i & 511;
  band[b*512 + k] = ((u32)(unsigned short)f2bf(hfin[(size_t)k*32 + b])<<16);
}

// ---------------- decoder scan: 48 worker WGs + DVFS fillers ----------------
// wg 0..15 : gh WG j: poll h_t -> MFMA (M=32 via 2 tiles) -> tagged GHt words
// wg 16..47: attn+GRU WG b: attention + pointwise, owns h[b] in LDS
// hband: u32 [2 slot][32 b][512 k]  word=(bf16<<16)|tag   (h_t tag = t)
// GHt:   u32 [32 b][1536 gcol]      word=(bf16<<16)|tag   (GH_t tag = t+1)
__global__ __launch_bounds__(512,1) void dec_scan(
  const short* __restrict__ gxeR,   // [(t*32+b)][1536] bf16 (incl bi_d)
  const short* __restrict__ encx,   // [b][1536][128] bf16
  const short* __restrict__ WhdT,   // [1536][512] bf16
  const float* __restrict__ brd,
  const short* __restrict__ Wa, const short* __restrict__ Uenc, const float* __restrict__ Va,
  const float* __restrict__ hfin,   // [512][32] f32
  u32* __restrict__ hband, u32* __restrict__ GHt,
  short* __restrict__ decRow, u32* __restrict__ dcnt)
{
  const int tid = threadIdx.x, wg = blockIdx.x;
  if (wg >= 48){ filler_spin(&dcnt[64], 48u); return; }

  // gh-WG shared
  __shared__ __align__(16) char Asb[32*1024];
  // attn-WG shared
  __shared__ float hs[512];
  __shared__ float gxc[1536];
  __shared__ float brA[1536];
  __shared__ float whp[128*5];
  __shared__ float whv[128];
  __shared__ float scp[128*5];
  __shared__ float sc[128];
  __shared__ float red[4];
  __shared__ float vL[128];
  __shared__ float aL[128];

  const int l = tid & 63, wv = tid >> 6;

  if (wg < 16){
    // ---- gh WG j: 6 waves x one 16-col n-tile x TWO 16-batch m-tiles ----
    const int j = wg;
    const int colbase = (wv>>1)*512 + j*32 + ((wv&1)<<4);   // valid for wv<6
    bf16x8 bfr[16];
    if (wv < 6){
      const short* bp = WhdT + (size_t)(colbase + (l&15))*512 + ((l>>4)<<3);
#pragma unroll
      for (int kt=0; kt<16; ++kt) bfr[kt] = *(const bf16x8*)(bp + kt*32);
    }
    const int sb = tid >> 4, sk0 = (tid & 15)*32;
    for (int t=0; t<128; ++t){
      // stage h_t (tagged poll-retry)
      {
        const u32* src = hband + (size_t)(t&1)*16384 + sb*512 + sk0;
        u32 w[32];
#pragma unroll
        for (int i=0;i<32;++i) w[i] = cohl4(src+i);
#pragma unroll
        for (int i=0;i<32;++i){ while ((w[i]&0xffffu) != (u32)t) w[i] = cohl4(src+i); }
#pragma unroll
        for (int i=0;i<16;++i){
          u32 p = (w[2*i]>>16) | (w[2*i+1] & 0xffff0000u);
          *(u32*)(Asb + (((u32)(sb*1024 + (sk0+2*i)*2)) ^ ((u32)(sb&15)<<4))) = p;
        }
      }
      __syncthreads();
      if (wv < 6){
        f32x4 acc0 = (f32x4){0.f,0.f,0.f,0.f};
        f32x4 acc1 = (f32x4){0.f,0.f,0.f,0.f};
#pragma unroll
        for (int kt=0; kt<16; ++kt){
          int kbyte = (kt*32 + ((l>>4)<<3))*2;
          int r0 = l & 15, r1 = 16 + (l & 15);
          bf16x8 af0 = *(const bf16x8*)(Asb + (((u32)(r0*1024 + kbyte)) ^ ((u32)(r0&15)<<4)));
          bf16x8 af1 = *(const bf16x8*)(Asb + (((u32)(r1*1024 + kbyte)) ^ ((u32)(r1&15)<<4)));
          acc0 = __builtin_amdgcn_mfma_f32_16x16x32_bf16(af0, bfr[kt], acc0, 0,0,0);
          acc1 = __builtin_amdgcn_mfma_f32_16x16x32_bf16(af1, bfr[kt], acc1, 0,0,0);
        }
        // publish: batch = m*16 + (l>>4)*4 + r, gcol = colbase + (l&15), tag t+1
#pragma unroll
        for (int r=0;r<4;++r){
          u32 wd0 = ((u32)(unsigned short)f2bf(acc0[r])<<16) | (u32)(t+1);
          cohs4(&GHt[(size_t)((l>>4)*4 + r)*1536 + colbase + (l&15)], wd0);
          u32 wd1 = ((u32)(unsigned short)f2bf(acc1[r])<<16) | (u32)(t+1);
          cohs4(&GHt[(size_t)(16 + (l>>4)*4 + r)*1536 + colbase + (l&15)], wd1);
        }
      }
      __syncthreads();   // protect Asb reuse
    }
    if (tid == 0) doneadd(&dcnt[64]);
  } else {
    // ---- attn+GRU WG, batch b ----
    const int b = wg - 16;
    u32 wa[64];
    {
      const u32* wp = (const u32*)(Wa + (size_t)(tid&127)*512 + (tid>>7)*128);
#pragma unroll
      for (int i=0;i<64;++i) wa[i] = wp[i];
    }
    u32 ue[16];
    {
      int s = tid & 127, aq = tid >> 7;
      const u32* up = (const u32*)(Uenc + ((size_t)(s*32 + b))*128 + aq*32);
#pragma unroll
      for (int i=0;i<16;++i) ue[i] = up[i];
    }
    if (tid < 128) vL[tid] = Va[tid];
    for (int i = tid; i < 1536; i += 512) brA[i] = brd[i];
    hs[tid] = hfin[(size_t)tid*32 + b];
    const short* eb = encx + (size_t)b*1536*128;
    __syncthreads();

    for (int t=0; t<128; ++t){
      // wh = h @ Wa^T (k split 4-way)  [h local in LDS]
      {
        int a = tid & 127, kq2 = tid >> 7;
        float p = 0.f;
        const float* hp2 = &hs[kq2*128];
#pragma unroll 8
        for (int i=0;i<64;++i){
          u32 w2 = wa[i];
          float2 h2 = *(const float2*)(hp2 + 2*i);
          p += bf2f((short)(w2 & 0xffff))*h2.x + bf2f((short)(w2 >> 16))*h2.y;
        }
        whp[a*5 + kq2] = p;
      }
      __syncthreads();
      if (tid < 128) whv[tid] = whp[tid*5]+whp[tid*5+1]+whp[tid*5+2]+whp[tid*5+3];
      __syncthreads();
      // score_s = sum_a tanh(wh_a + Uenc) * v_a (a split 4-way)
      {
        int s = tid & 127, aq = tid >> 7;
        float p = 0.f;
#pragma unroll 4
        for (int i=0;i<16;++i){
          u32 u2 = ue[i];
          int a0 = aq*32 + 2*i;
          p += tanh_fast(whv[a0]   + bf2f((short)(u2 & 0xffff))) * vL[a0];
          p += tanh_fast(whv[a0+1] + bf2f((short)(u2 >> 16)))    * vL[a0+1];
        }
        scp[s*5 + aq] = p;
      }
      __syncthreads();
      if (tid < 128) sc[tid] = scp[tid*5]+scp[tid*5+1]+scp[tid*5+2]+scp[tid*5+3];
      __syncthreads();
      float ev = 0.f;
      if (tid < 128){
        float v = sc[tid], mx = v;
#pragma unroll
        for (int d2=32; d2; d2>>=1) mx = fmaxf(mx, __shfl_xor(mx, d2));
        if ((tid & 63) == 0) red[tid>>6] = mx;
      }
      __syncthreads();
      if (tid < 128){
        float mx = fmaxf(red[0], red[1]);
        ev = __expf(sc[tid] - mx);
        float sm = ev;
#pragma unroll
        for (int d2=32; d2; d2>>=1) sm += __shfl_xor(sm, d2);
        if ((tid & 63) == 0) red[2 + (tid>>6)] = sm;
      }
      __syncthreads();
      if (tid < 128) aL[tid] = ev / (red[2] + red[3]);
      __syncthreads();
      // gxctx: 3 cols/thread from L2-resident ENCX slice
      {
        int col = tid*3;
        float a0=0.f, a1=0.f, a2=0.f;
        const short* e0 = eb + (size_t)col*128;
#pragma unroll
        for (int sb2=0; sb2<16; ++sb2){
          f32x4 av0 = *(const f32x4*)&aL[sb2*8];
          f32x4 av1 = *(const f32x4*)&aL[sb2*8+4];
          bf16x8 ev0 = *(const bf16x8*)(e0 + sb2*8);
          bf16x8 ev1 = *(const bf16x8*)(e0 + 128 + sb2*8);
          bf16x8 ev2 = *(const bf16x8*)(e0 + 256 + sb2*8);
#pragma unroll
          for (int i=0;i<4;++i){
            a0 += bf2f(ev0[i])*av0[i]; a1 += bf2f(ev1[i])*av0[i]; a2 += bf2f(ev2[i])*av0[i];
            a0 += bf2f(ev0[4+i])*av1[i]; a1 += bf2f(ev1[4+i])*av1[i]; a2 += bf2f(ev2[4+i])*av1[i];
          }
        }
        gxc[col] = a0; gxc[col+1] = a1; gxc[col+2] = a2;
      }
      __syncthreads();
      // prefetch gx (independent of GH)
      const short* gx = gxeR + ((size_t)t*32 + b)*1536;
      float gx0 = bf2f(gx[tid])        + gxc[tid];
      float gx1 = bf2f(gx[512 + tid])  + gxc[512 + tid];
      float gx2 = bf2f(gx[1024 + tid]) + gxc[1024 + tid];
      // poll own GH words (tag t+1), decode, pointwise, publish h_{t+1}
      short mybf;
      {
        const u32* gp = GHt + (size_t)b*1536 + tid;
        u32 g0 = cohl4(gp), g1 = cohl4(gp+512), g2 = cohl4(gp+1024);
        u32 want = (u32)(t+1);
        while ((g0&0xffffu) != want) g0 = cohl4(gp);
        while ((g1&0xffffu) != want) g1 = cohl4(gp+512);
        while ((g2&0xffffu) != want) g2 = cohl4(gp+1024);
        float gh0 = bf2f((short)(g0>>16));
        float gh1 = bf2f((short)(g1>>16));
        float gh2 = bf2f((short)(g2>>16));
        float z = sig_p(gx0 + gh0 + brA[tid]);
        float r = sig_p(gx1 + gh1 + brA[512 + tid]);
        float hcand = tanhf(gx2 + r*(gh2 + brA[1024 + tid]));
        float hp = hs[tid];
        float hn = z*hp + (1.f-z)*hcand;
        mybf = f2bf(hn);
        cohs4(&hband[(size_t)((t+1)&1)*16384 + b*512 + tid],
              ((u32)(unsigned short)mybf<<16) | (u32)(t+1));
        hs[tid] = hn;
      }
      decRow[((size_t)t*32 + b)*512 + tid] = mybf;   // off critical path
      __syncthreads();                               // hs ready for next wh
    }
    if (tid == 0) doneadd(&dcnt[64]);
  }
}

// ---------------- softmax finish ----------------
__global__ void scale_rows(float* __restrict__ out, const float* __restrict__ psum,
                           int ncols, int w){
  int r = blockIdx.x;
  __shared__ float ssum[256];
  float s = 0.f;
  for (int i = threadIdx.x; i < w; i += 256) s += psum[(size_t)r*w + i];
  ssum[threadIdx.x] = s; __syncthreads();
  for (int d = 128; d; d >>= 1){
    if (threadIdx.x < d) ssum[threadIdx.x] += ssum[threadIdx.x + d];
    __syncthreads();
  }
  float v = 1.f/ssum[0];
  float* p = out + (size_t)r*ncols;
  for (int i = threadIdx.x; i < ncols; i += 256) p[i] *= v;
}

// ---------------- host ----------------
extern "C" void kernel_launch(void* const* d_in, const int* in_sizes, int n_in,
                              void* d_out, int out_size, void* d_ws, size_t ws_size,
                              hipStream_t stream)
{
  const int*   tokens=(const int*)  d_in[0];
  const float* emb  =(const float*)d_in[1];
  const float* Wx_f =(const float*)d_in[2];
  const float* Wh_f =(const float*)d_in[3];
  const float* bi_f =(const float*)d_in[4];
  const float* br_f =(const float*)d_in[5];
  const float* Wx_b =(const float*)d_in[6];
  const float* Wh_b =(const float*)d_in[7];
  const float* bi_b =(const float*)d_in[8];
  const float* br_b =(const float*)d_in[9];
  const float* W_a  =(const float*)d_in[10];
  const float* U_a  =(const float*)d_in[11];
  const float* V_a  =(const float*)d_in[12];
  const float* Wx_d =(const float*)d_in[13];
  const float* Wh_d =(const float*)d_in[14];
  const float* bi_d =(const float*)d_in[15];
  const float* br_d =(const float*)d_in[16];
  const float* Wo   =(const float*)d_in[17];
  const float* bo   =(const float*)d_in[18];

  const int NV = 32001, NVP = 32128, NCB = 251;

  char* base = (char*)d_ws; size_t off = 0;
  auto alloc = [&](size_t bytes)->char*{
    off = (off + 255) & ~(size_t)255;
    char* p = base + off; off += bytes; return p;
  };
  u32*   dcnt   = (u32*)  alloc(512);                   // [0]=enc done, [64]=dec done
  u32*   band_e = (u32*)  alloc((size_t)2*2*16384*4);   // [2 dir][2 slot][32][512]
  u32*   band_d = (u32*)  alloc((size_t)2*16384*4);     // [2 slot][32][512]
  u32*   GHt    = (u32*)  alloc((size_t)32*1536*4);     // [32][1536]
  float* hfin   = (float*)alloc((size_t)512*32*4);
  short* X      = (short*)alloc((size_t)4096*256*2);
  short* WxfT   = (short*)alloc((size_t)1536*256*2);
  short* WxbT   = (short*)alloc((size_t)1536*256*2);
  short* WhfT   = (short*)alloc((size_t)1536*512*2);
  short* WhbT   = (short*)alloc((size_t)1536*512*2);
  short* WhdT   = (short*)alloc((size_t)1536*512*2);
  short* WxeT   = (short*)alloc((size_t)1536*1024*2);
  short* WxcT   = (short*)alloc((size_t)1536*1024*2);
  short* WoT    = (short*)alloc((size_t)NVP*512*2);
  short* UaB    = (short*)alloc((size_t)128*1024*2);
  short* WaB    = (short*)alloc((size_t)128*512*2);
  short* gxfT   = (short*)alloc((size_t)128*1536*32*2);
  short* gxbT   = (short*)alloc((size_t)128*1536*32*2);
  short* encT   = (short*)alloc((size_t)128*1024*32*2);
  short* encRow = (short*)alloc((size_t)4096*1024*2);
  short* Uenc   = (short*)alloc((size_t)4096*128*2);
  short* gxeR   = (short*)alloc((size_t)4096*1536*2);
  short* encxT1 = (short*)alloc((size_t)128*1536*32*2);
  short* encx   = (short*)alloc((size_t)32*1536*128*2);
  short* decRow = (short*)alloc((size_t)4096*512*2);
  float* psum   = (float*)alloc((size_t)4096*2*NCB*4);

  hipMemsetAsync(dcnt,   0, 512, stream);
  hipMemsetAsync(band_e, 0, (size_t)2*2*16384*4, stream);   // slot0 = h0 zeros, tag 0
  hipMemsetAsync(band_d, 0, (size_t)2*16384*4, stream);
  hipMemsetAsync(GHt,    0, (size_t)32*1536*4, stream);

  // weight conversions (all BT = [N][K] bf16)
  tconv<<<dim3(1536/32,256/32),dim3(32,8),0,stream>>>(Wx_f, WxfT, 256, 1536, 1536);
  tconv<<<dim3(1536/32,256/32),dim3(32,8),0,stream>>>(Wx_b, WxbT, 256, 1536, 1536);
  tconv<<<dim3(1536/32,512/32),dim3(32,8),0,stream>>>(Wh_f, WhfT, 512, 1536, 1536);
  tconv<<<dim3(1536/32,512/32),dim3(32,8),0,stream>>>(Wh_b, WhbT, 512, 1536, 1536);
  tconv<<<dim3(1536/32,512/32),dim3(32,8),0,stream>>>(Wh_d, WhdT, 512, 1536, 1536);
  tconv<<<dim3(1536/32,1024/32),dim3(32,8),0,stream>>>(Wx_d,                    WxeT, 1024, 1536, 1536);
  tconv<<<dim3(1536/32,1024/32),dim3(32,8),0,stream>>>(Wx_d+(size_t)1024*1536,  WxcT, 1024, 1536, 1536);
  tconv<<<dim3(NVP/32,512/32),dim3(32,8),0,stream>>>(Wo, WoT, 512, NV, NVP);
  cvt1d<<<(128*512+255)/256,256,0,stream>>>(W_a, WaB, 128*512);
  cvt1d<<<(128*1024+255)/256,256,0,stream>>>(U_a, UaB, 128*1024);

  embed_k<<<4096,256,0,stream>>>(tokens, emb, X);

  gemm_k<1><<<dim3(12,32),256,0,stream>>>(X, WxfT, bi_f, gxfT, nullptr, 1536, 256, 1536);
  gemm_k<1><<<dim3(12,32),256,0,stream>>>(X, WxbT, bi_b, gxbT, nullptr, 1536, 256, 1536);

  enc_scan<<<512,512,0,stream>>>(gxfT, gxbT, WhfT, WhbT, br_f, br_b,
                                 band_e, hfin, encT, dcnt);

  btrans<<<dim3(1024/32,128),dim3(32,8),0,stream>>>(encT, encRow, 1024);

  gemm_k<3><<<dim3(1,32),256,0,stream>>>(encRow, UaB, nullptr, Uenc, nullptr, 128, 1024, 128);
  gemm_k<3><<<dim3(12,32),256,0,stream>>>(encRow, WxeT, bi_d, gxeR, nullptr, 1536, 1024, 1536);
  gemm_k<1><<<dim3(12,32),256,0,stream>>>(encRow, WxcT, nullptr, encxT1, nullptr, 1536, 1024, 1536);
  etrans<<<1536,256,0,stream>>>(encxT1, encx);

  dec_init<<<64,256,0,stream>>>(hfin, band_d);

  dec_scan<<<512,512,0,stream>>>(gxeR, encx, WhdT, br_d, WaB, Uenc, V_a,
                                 hfin, band_d, GHt, decRow, dcnt);

  gemm_k<2><<<dim3(NCB,32),256,0,stream>>>(decRow, WoT, bo, d_out, psum, NV, 512, NV);

  scale_rows<<<4096,256,0,stream>>>((float*)d_out, psum, NV, 2*NCB);
}